// Round 1
// baseline (19938.632 us; speedup 1.0000x reference)
//
#include <hip/hip_runtime.h>
#include <cstdint>
#include <cstddef>

namespace {

constexpr int B = 64, S = 128, T = 64, V = 32000, E = 512, H = 512;
constexpr int G4 = 2048;          // 4*H gate width
constexpr int TM1 = T - 1;        // 63 decoder steps
constexpr int CHUNK = 32;         // encoder time chunk for X staging
constexpr int BH = B * H;         // 32768

__device__ __forceinline__ float sigf(float x) { return 1.0f / (1.0f + expf(-x)); }

// ---------- transpose: src [2][G4][E] -> dst [2][E][G4] ----------
__global__ __launch_bounds__(256)
void transpose_k(const float* __restrict__ src, float* __restrict__ dst)
{
    __shared__ float tile[32][33];
    int z = blockIdx.z;
    const float* s = src + (size_t)z * G4 * E;
    float* d = dst + (size_t)z * E * G4;
    int j0 = blockIdx.x * 32;   // over G4
    int e0 = blockIdx.y * 32;   // over E
    int tx = threadIdx.x, ty = threadIdx.y;  // (32,8)
#pragma unroll
    for (int r = 0; r < 4; ++r)
        tile[ty + 8 * r][tx] = s[(size_t)(j0 + ty + 8 * r) * E + e0 + tx];
    __syncthreads();
#pragma unroll
    for (int r = 0; r < 4; ++r)
        d[(size_t)(e0 + ty + 8 * r) * G4 + j0 + tx] = tile[tx][ty + 8 * r];
}

// ---------- GEMM: C[M][N] = A[M][512] * Wt[N][512]^T + bias[N] ----------
// tokmode: A row m -> src_emb[xseq[b*S+t]] with (t,b) decoded from (m0+m)
__global__ __launch_bounds__(256)
void gemm_k(const float* __restrict__ A, const float* __restrict__ Wt,
            const float* __restrict__ bias, float* __restrict__ C,
            int N, int tokmode, const int* __restrict__ xseq, int m0)
{
    constexpr int K = 512, BM = 64, BN = 128, BK = 16;
    __shared__ __align__(16) float As[BK][BM + 4];
    __shared__ __align__(16) float Bs[BK][BN + 4];
    int tid = threadIdx.x;
    int bm = blockIdx.y * BM, bn = blockIdx.x * BN;
    int tx = tid & 15, ty = tid >> 4;
    float acc[4][8] = {};

    int lm = tid >> 2, lk = (tid & 3) << 2;     // A loader: 64 rows x 16 k
    const float* Arow;
    {
        int m = bm + lm;
        if (tokmode) { int mg = m0 + m; int t = mg >> 6, b = mg & 63;
                       Arow = A + (size_t)xseq[b * S + t] * K; }
        else Arow = A + (size_t)m * K;
    }
    int ln = tid >> 1, lkb = (tid & 1) << 3;    // B loader: 128 rows x 16 k
    const float* Brow = Wt + (size_t)(bn + ln) * K;

    for (int k0 = 0; k0 < K; k0 += BK) {
        float4 av = *(const float4*)(Arow + k0 + lk);
        As[lk + 0][lm] = av.x; As[lk + 1][lm] = av.y;
        As[lk + 2][lm] = av.z; As[lk + 3][lm] = av.w;
        float4 bv0 = *(const float4*)(Brow + k0 + lkb);
        float4 bv1 = *(const float4*)(Brow + k0 + lkb + 4);
        Bs[lkb + 0][ln] = bv0.x; Bs[lkb + 1][ln] = bv0.y;
        Bs[lkb + 2][ln] = bv0.z; Bs[lkb + 3][ln] = bv0.w;
        Bs[lkb + 4][ln] = bv1.x; Bs[lkb + 5][ln] = bv1.y;
        Bs[lkb + 6][ln] = bv1.z; Bs[lkb + 7][ln] = bv1.w;
        __syncthreads();
#pragma unroll
        for (int kk = 0; kk < BK; ++kk) {
            const float4 a4  = *(const float4*)&As[kk][ty * 4];
            const float4 b4a = *(const float4*)&Bs[kk][tx * 8];
            const float4 b4b = *(const float4*)&Bs[kk][tx * 8 + 4];
            const float a[4]  = {a4.x, a4.y, a4.z, a4.w};
            const float bb[8] = {b4a.x, b4a.y, b4a.z, b4a.w,
                                 b4b.x, b4b.y, b4b.z, b4b.w};
#pragma unroll
            for (int i = 0; i < 4; ++i)
#pragma unroll
                for (int j = 0; j < 8; ++j)
                    acc[i][j] = fmaf(a[i], bb[j], acc[i][j]);
        }
        __syncthreads();
    }
#pragma unroll
    for (int i = 0; i < 4; ++i) {
        size_t crow = (size_t)(bm + ty * 4 + i) * N + bn;
#pragma unroll
        for (int j = 0; j < 8; ++j) {
            int nn = tx * 8 + j;
            C[crow + nn] = acc[i][j] + bias[bn + nn];
        }
    }
}

// ---------- encoder LSTM step (x-part precomputed in Xc, incl. bias) ----------
// grid (8,16), block 256. thread: khl=tid&63, gpair=(tid>>6)&1, bsel=tid>>7
__global__ __launch_bounds__(256)
void enc_step_k(const float* __restrict__ Xc, const float* __restrict__ WhhT,
                const float* __restrict__ h_in, float* __restrict__ h_out,
                float* __restrict__ c, float* __restrict__ out0,
                const int* __restrict__ x_len, int t, int tloc)
{
    __shared__ float gs[4][4][64];
    int tid = threadIdx.x;
    int khl = tid & 63;
    int kh = blockIdx.x * 64 + khl;
    int gpair = (tid >> 6) & 1, g0 = gpair * 2;
    int bsel = tid >> 7;
    int b0 = blockIdx.y * 4 + bsel * 2;

    const float* X0 = Xc + (size_t)(tloc * B + b0) * G4;
    const float* X1 = X0 + G4;
    float acc00 = X0[(g0 + 0) * H + kh], acc01 = X1[(g0 + 0) * H + kh];
    float acc10 = X0[(g0 + 1) * H + kh], acc11 = X1[(g0 + 1) * H + kh];

    const float* h0p = h_in + (size_t)b0 * H;
    const float* h1p = h0p + H;
    const float* wp = WhhT + (size_t)g0 * H + kh;
    for (int e = 0; e < E; e += 4) {
        float4 ha = *(const float4*)(h0p + e);
        float4 hb = *(const float4*)(h1p + e);
#pragma unroll
        for (int ei = 0; ei < 4; ++ei) {
            float w0 = wp[(size_t)(e + ei) * G4];
            float w1 = wp[(size_t)(e + ei) * G4 + H];
            float xa = ((const float*)&ha)[ei];
            float xb = ((const float*)&hb)[ei];
            acc00 = fmaf(w0, xa, acc00); acc01 = fmaf(w0, xb, acc01);
            acc10 = fmaf(w1, xa, acc10); acc11 = fmaf(w1, xb, acc11);
        }
    }
    gs[g0 + 0][bsel * 2 + 0][khl] = acc00;
    gs[g0 + 0][bsel * 2 + 1][khl] = acc01;
    gs[g0 + 1][bsel * 2 + 0][khl] = acc10;
    gs[g0 + 1][bsel * 2 + 1][khl] = acc11;
    __syncthreads();
    int ku = tid & 63;
    int bu = tid >> 6;                        // 0..3
    int bg = blockIdx.y * 4 + bu;
    int khg = blockIdx.x * 64 + ku;
    float gi = gs[0][bu][ku], gf = gs[1][bu][ku];
    float gg = gs[2][bu][ku], go = gs[3][bu][ku];
    size_t idx = (size_t)bg * H + khg;
    float cold = c[idx];
    float c2 = sigf(gf) * cold + sigf(gi) * tanhf(gg);
    float h2 = sigf(go) * tanhf(c2);
    bool mk = t < x_len[bg];
    float hold = h_in[idx];
    h2 = mk ? h2 : hold;
    c2 = mk ? c2 : cold;
    h_out[idx] = h2;
    c[idx] = c2;
    if (out0) out0[(size_t)(t * B + bg) * H + khg] = h2;
}

// ---------- decoder LSTM step (x via gather or direct, full x+h dots) ----------
__global__ __launch_bounds__(256)
void dec_step_k(const float* __restrict__ xbase, const int* __restrict__ inp,
                const float* __restrict__ WihT, const float* __restrict__ WhhT,
                const float* __restrict__ bias,
                const float* __restrict__ h_in, float* __restrict__ h_out,
                float* __restrict__ c)
{
    __shared__ float gs[4][4][64];
    int tid = threadIdx.x;
    int khl = tid & 63;
    int kh = blockIdx.x * 64 + khl;
    int gpair = (tid >> 6) & 1, g0 = gpair * 2;
    int bsel = tid >> 7;
    int b0 = blockIdx.y * 4 + bsel * 2;

    const float* xa_p = inp ? xbase + (size_t)inp[b0] * E     : xbase + (size_t)b0 * H;
    const float* xb_p = inp ? xbase + (size_t)inp[b0 + 1] * E : xbase + (size_t)(b0 + 1) * H;
    float bias0 = bias[(g0 + 0) * H + kh];
    float bias1 = bias[(g0 + 1) * H + kh];
    float acc00 = bias0, acc01 = bias0, acc10 = bias1, acc11 = bias1;

    const float* wip = WihT + (size_t)g0 * H + kh;
    const float* whp = WhhT + (size_t)g0 * H + kh;
    const float* h0p = h_in + (size_t)b0 * H;
    const float* h1p = h0p + H;
    for (int e = 0; e < E; e += 4) {
        float4 xa = *(const float4*)(xa_p + e);
        float4 xb = *(const float4*)(xb_p + e);
        float4 ha = *(const float4*)(h0p + e);
        float4 hb = *(const float4*)(h1p + e);
#pragma unroll
        for (int ei = 0; ei < 4; ++ei) {
            size_t eo = (size_t)(e + ei) * G4;
            float wi0 = wip[eo], wi1 = wip[eo + H];
            float wh0 = whp[eo], wh1 = whp[eo + H];
            float va = ((const float*)&xa)[ei], vb = ((const float*)&xb)[ei];
            float ua = ((const float*)&ha)[ei], ub = ((const float*)&hb)[ei];
            acc00 = fmaf(wi0, va, fmaf(wh0, ua, acc00));
            acc01 = fmaf(wi0, vb, fmaf(wh0, ub, acc01));
            acc10 = fmaf(wi1, va, fmaf(wh1, ua, acc10));
            acc11 = fmaf(wi1, vb, fmaf(wh1, ub, acc11));
        }
    }
    gs[g0 + 0][bsel * 2 + 0][khl] = acc00;
    gs[g0 + 0][bsel * 2 + 1][khl] = acc01;
    gs[g0 + 1][bsel * 2 + 0][khl] = acc10;
    gs[g0 + 1][bsel * 2 + 1][khl] = acc11;
    __syncthreads();
    int ku = tid & 63;
    int bu = tid >> 6;
    int bg = blockIdx.y * 4 + bu;
    int khg = blockIdx.x * 64 + ku;
    float gi = gs[0][bu][ku], gf = gs[1][bu][ku];
    float gg = gs[2][bu][ku], go = gs[3][bu][ku];
    size_t idx = (size_t)bg * H + khg;
    float cold = c[idx];
    float c2 = sigf(gf) * cold + sigf(gi) * tanhf(gg);
    float h2 = sigf(go) * tanhf(c2);
    h_out[idx] = h2;
    c[idx] = c2;
}

// ---------- generator reduce: max/argmax, logsumexp, gold, next input ----------
__global__ __launch_bounds__(256)
void dec_reduce_k(const float* __restrict__ logits, const int* __restrict__ y_seqs,
                  const int* __restrict__ teacher, int* __restrict__ inp,
                  float* __restrict__ outp, int t)
{
    __shared__ float sv[256];
    __shared__ int   si[256];
    __shared__ float ss[256];
    int b = blockIdx.x, tid = threadIdx.x;
    const float* row = logits + (size_t)b * V;
    float vmax = -3.4e38f; int imax = V;
    for (int v = tid; v < V; v += 256) {
        float x = row[v];
        if (x > vmax || (x == vmax && v < imax)) { vmax = x; imax = v; }
    }
    sv[tid] = vmax; si[tid] = imax;
    __syncthreads();
    for (int off = 128; off > 0; off >>= 1) {
        if (tid < off) {
            float v2 = sv[tid + off]; int i2 = si[tid + off];
            if (v2 > sv[tid] || (v2 == sv[tid] && i2 < si[tid])) { sv[tid] = v2; si[tid] = i2; }
        }
        __syncthreads();
    }
    float m = sv[0];
    float s = 0.f;
    for (int v = tid; v < V; v += 256) s += expf(row[v] - m);
    ss[tid] = s;
    __syncthreads();
    for (int off = 128; off > 0; off >>= 1) {
        if (tid < off) ss[tid] += ss[tid + off];
        __syncthreads();
    }
    if (tid == 0) {
        float lse = m + logf(ss[0]);
        int y = y_seqs[b * T + (t + 1)];
        outp[b * TM1 + t] = row[y] - lse;
        inp[b] = (teacher[t] > 0) ? y : si[0];
    }
}

__global__ void init_inp_k(int* inp) { if (threadIdx.x < B) inp[threadIdx.x] = 1; }

} // namespace

extern "C" void kernel_launch(void* const* d_in, const int* in_sizes, int n_in,
                              void* d_out, int out_size, void* d_ws, size_t ws_size,
                              hipStream_t stream)
{
    (void)in_sizes; (void)n_in; (void)out_size;
    const int*   x_seqs  = (const int*)  d_in[0];
    const int*   x_len   = (const int*)  d_in[1];
    const int*   y_seqs  = (const int*)  d_in[2];
    const int*   teacher = (const int*)  d_in[3];
    const float* src_emb = (const float*)d_in[4];
    const float* tgt_emb = (const float*)d_in[5];
    const float* eWih    = (const float*)d_in[6];
    const float* eWhh    = (const float*)d_in[7];
    const float* eb      = (const float*)d_in[8];
    const float* dWih    = (const float*)d_in[9];
    const float* dWhh    = (const float*)d_in[10];
    const float* db      = (const float*)d_in[11];
    const float* genW    = (const float*)d_in[12];
    const float* genb    = (const float*)d_in[13];
    float* out = (float*)d_out;

    float* w = (float*)d_ws;
    size_t off = 0;
    auto take = [&](size_t n) { float* p = w + off; off += n; return p; };
    float* Xc     = take((size_t)CHUNK * B * G4);   // x-part of gates, one time-chunk
    float* out0   = take((size_t)S * B * H);        // encoder layer-0 outputs
    float* eWhhT  = take((size_t)2 * E * G4);
    float* dWhhT  = take((size_t)2 * E * G4);
    float* dWihT  = take((size_t)2 * E * G4);
    float* hping  = take(2 * (size_t)BH);
    float* cenc   = take(2 * (size_t)BH);
    float* dech   = take(4 * (size_t)BH);           // [layer][slot][B*H]
    float* decc   = take(2 * (size_t)BH);
    float* logits = take((size_t)B * V);
    int*   inp    = (int*)take(256);
    if (ws_size < off * sizeof(float)) return;      // ws too small: fail visibly

    dim3 tpb256(256), tpb32x8(32, 8);
    transpose_k<<<dim3(G4 / 32, E / 32, 2), tpb32x8, 0, stream>>>(eWhh, eWhhT);
    transpose_k<<<dim3(G4 / 32, E / 32, 2), tpb32x8, 0, stream>>>(dWhh, dWhhT);
    transpose_k<<<dim3(G4 / 32, E / 32, 2), tpb32x8, 0, stream>>>(dWih, dWihT);
    hipMemsetAsync(hping, 0, 2 * BH * sizeof(float), stream);
    hipMemsetAsync(cenc,  0, 2 * BH * sizeof(float), stream);

    // ---------------- encoder: 2 layers, chunked x-part GEMM + per-step scan ----
    for (int l = 0; l < 2; ++l) {
        const float* WihL  = eWih  + (size_t)l * G4 * E;
        const float* WhhTL = eWhhT + (size_t)l * E * G4;
        const float* bL    = eb + l * G4;
        float* cL = cenc + (size_t)l * BH;
        float* o0 = (l == 0) ? out0 : nullptr;
        for (int c0 = 0; c0 < S; c0 += CHUNK) {
            if (l == 0)
                gemm_k<<<dim3(G4 / 128, CHUNK * B / 64), tpb256, 0, stream>>>(
                    src_emb, WihL, bL, Xc, G4, 1, x_seqs, c0 * B);
            else
                gemm_k<<<dim3(G4 / 128, CHUNK * B / 64), tpb256, 0, stream>>>(
                    out0 + (size_t)c0 * B * H, WihL, bL, Xc, G4, 0, nullptr, 0);
            for (int t = c0; t < c0 + CHUNK; ++t)
                enc_step_k<<<dim3(8, 16), tpb256, 0, stream>>>(
                    Xc, WhhTL, hping + (size_t)(t & 1) * BH,
                    hping + (size_t)((t + 1) & 1) * BH, cL, o0, x_len, t, t - c0);
        }
        // final h is in slot ((S-1)+1)&1 == 0
        hipMemcpyAsync(dech + (size_t)(l * 2) * BH, hping, BH * sizeof(float),
                       hipMemcpyDeviceToDevice, stream);
        hipMemcpyAsync(decc + (size_t)l * BH, cL, BH * sizeof(float),
                       hipMemcpyDeviceToDevice, stream);
        if (l == 0) hipMemsetAsync(hping, 0, 2 * BH * sizeof(float), stream);
    }

    // ---------------- decoder: 63 steps -----------------------------------------
    init_inp_k<<<1, 64, 0, stream>>>(inp);
    for (int t = 0; t < TM1; ++t) {
        int si_ = t & 1, so_ = (t + 1) & 1;
        dec_step_k<<<dim3(8, 16), tpb256, 0, stream>>>(
            tgt_emb, inp, dWihT, dWhhT, db,
            dech + (size_t)si_ * BH, dech + (size_t)so_ * BH, decc);
        dec_step_k<<<dim3(8, 16), tpb256, 0, stream>>>(
            dech + (size_t)so_ * BH, nullptr,
            dWihT + (size_t)E * G4, dWhhT + (size_t)E * G4, db + G4,
            dech + (size_t)(2 + si_) * BH, dech + (size_t)(2 + so_) * BH, decc + BH);
        gemm_k<<<dim3(V / 128, 1), tpb256, 0, stream>>>(
            dech + (size_t)(2 + so_) * BH, genW, genb, logits, V, 0, nullptr, 0);
        dec_reduce_k<<<64, tpb256, 0, stream>>>(logits, y_seqs, teacher, inp, out, t);
    }
}

// Round 2
// 15754.933 us; speedup vs baseline: 1.2655x; 1.2655x over previous
//
#include <hip/hip_runtime.h>
#include <hip/hip_bf16.h>
#include <cstdint>
#include <cstddef>

namespace {

constexpr int B = 64, S = 128, T = 64, V = 32000, E = 512, H = 512;
constexpr int G4 = 2048;          // 4*H gate width
constexpr int TM1 = T - 1;        // 63 decoder steps
constexpr int CHUNK = 32;         // encoder time chunk for X staging
constexpr int BH = B * H;         // 32768
constexpr int NT = 128;           // generator N-tile
constexpr int NTILES = V / NT;    // 250
constexpr float MARGIN = 0.02f;   // bf16-argmax refinement margin (~37 sigma)

typedef __attribute__((ext_vector_type(8))) short short8v;
typedef __attribute__((ext_vector_type(4))) float f32x4;

struct Partial { float top1, top2; int i1, i2; float sumexp, gold; }; // 24B

__device__ __forceinline__ float sigf(float x) { return 1.0f / (1.0f + expf(-x)); }

// ---------- transpose: src [2][G4][E] -> dst [2][E][G4] ----------
__global__ __launch_bounds__(256)
void transpose_k(const float* __restrict__ src, float* __restrict__ dst)
{
    __shared__ float tile[32][33];
    int z = blockIdx.z;
    const float* s = src + (size_t)z * G4 * E;
    float* d = dst + (size_t)z * E * G4;
    int j0 = blockIdx.x * 32;   // over G4
    int e0 = blockIdx.y * 32;   // over E
    int tx = threadIdx.x, ty = threadIdx.y;  // (32,8)
#pragma unroll
    for (int r = 0; r < 4; ++r)
        tile[ty + 8 * r][tx] = s[(size_t)(j0 + ty + 8 * r) * E + e0 + tx];
    __syncthreads();
#pragma unroll
    for (int r = 0; r < 4; ++r)
        d[(size_t)(e0 + ty + 8 * r) * G4 + j0 + tx] = tile[tx][ty + 8 * r];
}

// ---------- f32 GEMM (encoder x-part): C[M][N] = A[M][512]*Wt[N][512]^T + b ----
__global__ __launch_bounds__(256)
void gemm_k(const float* __restrict__ A, const float* __restrict__ Wt,
            const float* __restrict__ bias, float* __restrict__ C,
            int N, int tokmode, const int* __restrict__ xseq, int m0)
{
    constexpr int K = 512, BM = 64, BN = 128, BK = 16;
    __shared__ __align__(16) float As[BK][BM + 4];
    __shared__ __align__(16) float Bs[BK][BN + 4];
    int tid = threadIdx.x;
    int bm = blockIdx.y * BM, bn = blockIdx.x * BN;
    int tx = tid & 15, ty = tid >> 4;
    float acc[4][8] = {};

    int lm = tid >> 2, lk = (tid & 3) << 2;
    const float* Arow;
    {
        int m = bm + lm;
        if (tokmode) { int mg = m0 + m; int tt = mg >> 6, b = mg & 63;
                       Arow = A + (size_t)xseq[b * S + tt] * K; }
        else Arow = A + (size_t)m * K;
    }
    int ln = tid >> 1, lkb = (tid & 1) << 3;
    const float* Brow = Wt + (size_t)(bn + ln) * K;

    for (int k0 = 0; k0 < K; k0 += BK) {
        float4 av = *(const float4*)(Arow + k0 + lk);
        As[lk + 0][lm] = av.x; As[lk + 1][lm] = av.y;
        As[lk + 2][lm] = av.z; As[lk + 3][lm] = av.w;
        float4 bv0 = *(const float4*)(Brow + k0 + lkb);
        float4 bv1 = *(const float4*)(Brow + k0 + lkb + 4);
        Bs[lkb + 0][ln] = bv0.x; Bs[lkb + 1][ln] = bv0.y;
        Bs[lkb + 2][ln] = bv0.z; Bs[lkb + 3][ln] = bv0.w;
        Bs[lkb + 4][ln] = bv1.x; Bs[lkb + 5][ln] = bv1.y;
        Bs[lkb + 6][ln] = bv1.z; Bs[lkb + 7][ln] = bv1.w;
        __syncthreads();
#pragma unroll
        for (int kk = 0; kk < BK; ++kk) {
            const float4 a4  = *(const float4*)&As[kk][ty * 4];
            const float4 b4a = *(const float4*)&Bs[kk][tx * 8];
            const float4 b4b = *(const float4*)&Bs[kk][tx * 8 + 4];
            const float a[4]  = {a4.x, a4.y, a4.z, a4.w};
            const float bb[8] = {b4a.x, b4a.y, b4a.z, b4a.w,
                                 b4b.x, b4b.y, b4b.z, b4b.w};
#pragma unroll
            for (int i = 0; i < 4; ++i)
#pragma unroll
                for (int j = 0; j < 8; ++j)
                    acc[i][j] = fmaf(a[i], bb[j], acc[i][j]);
        }
        __syncthreads();
    }
#pragma unroll
    for (int i = 0; i < 4; ++i) {
        size_t crow = (size_t)(bm + ty * 4 + i) * N + bn;
#pragma unroll
        for (int j = 0; j < 8; ++j) {
            int nn = tx * 8 + j;
            C[crow + nn] = acc[i][j] + bias[bn + nn];
        }
    }
}

// ---------- encoder LSTM step (x-part precomputed in Xc, incl. bias) ----------
__global__ __launch_bounds__(256)
void enc_step_k(const float* __restrict__ Xc, const float* __restrict__ WhhT,
                const float* __restrict__ h_in, float* __restrict__ h_out,
                float* __restrict__ c, float* __restrict__ out0,
                const int* __restrict__ x_len, int t, int tloc)
{
    __shared__ float gs[4][4][64];
    int tid = threadIdx.x;
    int khl = tid & 63;
    int kh = blockIdx.x * 64 + khl;
    int gpair = (tid >> 6) & 1, g0 = gpair * 2;
    int bsel = tid >> 7;
    int b0 = blockIdx.y * 4 + bsel * 2;

    const float* X0 = Xc + (size_t)(tloc * B + b0) * G4;
    const float* X1 = X0 + G4;
    float acc00 = X0[(g0 + 0) * H + kh], acc01 = X1[(g0 + 0) * H + kh];
    float acc10 = X0[(g0 + 1) * H + kh], acc11 = X1[(g0 + 1) * H + kh];

    const float* h0p = h_in + (size_t)b0 * H;
    const float* h1p = h0p + H;
    const float* wp = WhhT + (size_t)g0 * H + kh;
    for (int e = 0; e < E; e += 4) {
        float4 ha = *(const float4*)(h0p + e);
        float4 hb = *(const float4*)(h1p + e);
#pragma unroll
        for (int ei = 0; ei < 4; ++ei) {
            float w0 = wp[(size_t)(e + ei) * G4];
            float w1 = wp[(size_t)(e + ei) * G4 + H];
            float xa = ((const float*)&ha)[ei];
            float xb = ((const float*)&hb)[ei];
            acc00 = fmaf(w0, xa, acc00); acc01 = fmaf(w0, xb, acc01);
            acc10 = fmaf(w1, xa, acc10); acc11 = fmaf(w1, xb, acc11);
        }
    }
    gs[g0 + 0][bsel * 2 + 0][khl] = acc00;
    gs[g0 + 0][bsel * 2 + 1][khl] = acc01;
    gs[g0 + 1][bsel * 2 + 0][khl] = acc10;
    gs[g0 + 1][bsel * 2 + 1][khl] = acc11;
    __syncthreads();
    int ku = tid & 63;
    int bu = tid >> 6;
    int bg = blockIdx.y * 4 + bu;
    int khg = blockIdx.x * 64 + ku;
    float gi = gs[0][bu][ku], gf = gs[1][bu][ku];
    float gg = gs[2][bu][ku], go = gs[3][bu][ku];
    size_t idx = (size_t)bg * H + khg;
    float cold = c[idx];
    float c2 = sigf(gf) * cold + sigf(gi) * tanhf(gg);
    float h2 = sigf(go) * tanhf(c2);
    bool mk = t < x_len[bg];
    float hold = h_in[idx];
    h2 = mk ? h2 : hold;
    c2 = mk ? c2 : cold;
    h_out[idx] = h2;
    c[idx] = c2;
    if (out0) out0[(size_t)(t * B + bg) * H + khg] = h2;
}

// ---------- decoder LSTM step (f32; layer1 also emits bf16 h for generator) ----
__global__ __launch_bounds__(256)
void dec_step_k(const float* __restrict__ xbase, const int* __restrict__ inp,
                const float* __restrict__ WihT, const float* __restrict__ WhhT,
                const float* __restrict__ bias,
                const float* __restrict__ h_in, float* __restrict__ h_out,
                float* __restrict__ c, __hip_bfloat16* __restrict__ hbf)
{
    __shared__ float gs[4][4][64];
    int tid = threadIdx.x;
    int khl = tid & 63;
    int kh = blockIdx.x * 64 + khl;
    int gpair = (tid >> 6) & 1, g0 = gpair * 2;
    int bsel = tid >> 7;
    int b0 = blockIdx.y * 4 + bsel * 2;

    const float* xa_p = inp ? xbase + (size_t)inp[b0] * E     : xbase + (size_t)b0 * H;
    const float* xb_p = inp ? xbase + (size_t)inp[b0 + 1] * E : xbase + (size_t)(b0 + 1) * H;
    float bias0 = bias[(g0 + 0) * H + kh];
    float bias1 = bias[(g0 + 1) * H + kh];
    float acc00 = bias0, acc01 = bias0, acc10 = bias1, acc11 = bias1;

    const float* wip = WihT + (size_t)g0 * H + kh;
    const float* whp = WhhT + (size_t)g0 * H + kh;
    const float* h0p = h_in + (size_t)b0 * H;
    const float* h1p = h0p + H;
    for (int e = 0; e < E; e += 4) {
        float4 xa = *(const float4*)(xa_p + e);
        float4 xb = *(const float4*)(xb_p + e);
        float4 ha = *(const float4*)(h0p + e);
        float4 hb = *(const float4*)(h1p + e);
#pragma unroll
        for (int ei = 0; ei < 4; ++ei) {
            size_t eo = (size_t)(e + ei) * G4;
            float wi0 = wip[eo], wi1 = wip[eo + H];
            float wh0 = whp[eo], wh1 = whp[eo + H];
            float va = ((const float*)&xa)[ei], vb = ((const float*)&xb)[ei];
            float ua = ((const float*)&ha)[ei], ub = ((const float*)&hb)[ei];
            acc00 = fmaf(wi0, va, fmaf(wh0, ua, acc00));
            acc01 = fmaf(wi0, vb, fmaf(wh0, ub, acc01));
            acc10 = fmaf(wi1, va, fmaf(wh1, ua, acc10));
            acc11 = fmaf(wi1, vb, fmaf(wh1, ub, acc11));
        }
    }
    gs[g0 + 0][bsel * 2 + 0][khl] = acc00;
    gs[g0 + 0][bsel * 2 + 1][khl] = acc01;
    gs[g0 + 1][bsel * 2 + 0][khl] = acc10;
    gs[g0 + 1][bsel * 2 + 1][khl] = acc11;
    __syncthreads();
    int ku = tid & 63;
    int bu = tid >> 6;
    int bg = blockIdx.y * 4 + bu;
    int khg = blockIdx.x * 64 + ku;
    float gi = gs[0][bu][ku], gf = gs[1][bu][ku];
    float gg = gs[2][bu][ku], go = gs[3][bu][ku];
    size_t idx = (size_t)bg * H + khg;
    float cold = c[idx];
    float c2 = sigf(gf) * cold + sigf(gi) * tanhf(gg);
    float h2 = sigf(go) * tanhf(c2);
    h_out[idx] = h2;
    c[idx] = c2;
    if (hbf) hbf[idx] = __float2bfloat16(h2);
}

// ---------- f32 -> bf16 convert (genW, once per launch) ----------
__global__ __launch_bounds__(256)
void convert_bf16_k(const float* __restrict__ src, __hip_bfloat16* __restrict__ dst, int n)
{
    int i = (blockIdx.x * 256 + threadIdx.x) * 8;
    if (i + 8 > n) return;
    float4 a = *(const float4*)(src + i);
    float4 b = *(const float4*)(src + i + 4);
    __hip_bfloat16 tmp[8];
    tmp[0] = __float2bfloat16(a.x); tmp[1] = __float2bfloat16(a.y);
    tmp[2] = __float2bfloat16(a.z); tmp[3] = __float2bfloat16(a.w);
    tmp[4] = __float2bfloat16(b.x); tmp[5] = __float2bfloat16(b.y);
    tmp[6] = __float2bfloat16(b.z); tmp[7] = __float2bfloat16(b.w);
    *(short8v*)(dst + i) = *(const short8v*)tmp;
}

// ---------- generator: bf16 MFMA GEMM + fused per-tile softmax partials --------
// grid: NTILES blocks x 256 threads (4 waves). wave w: cols n0+w*32 .. +31, rows 0..63
__global__ __launch_bounds__(256)
void gen_fused_k(const __hip_bfloat16* __restrict__ hbf,   // [64][512]
                 const __hip_bfloat16* __restrict__ Wbf,   // [V][512]
                 const float* __restrict__ genb,
                 const int* __restrict__ y_seqs, int t,
                 Partial* __restrict__ part)                // [NTILES][B]
{
    __shared__ float lds[64][NT + 4];
    __shared__ float pv1[64][4], pv2[64][4], psum[64][4], mrow[64];
    __shared__ int   pi1[64][4], pi2[64][4];

    int tid = threadIdx.x;
    int wave = tid >> 6, lane = tid & 63;
    int n0 = blockIdx.x * NT;
    int lr = lane & 15;
    int kg = (lane >> 4) * 8;

    f32x4 acc[4][2];
    const f32x4 zero = {0.f, 0.f, 0.f, 0.f};
#pragma unroll
    for (int i = 0; i < 4; ++i)
#pragma unroll
        for (int j = 0; j < 2; ++j) acc[i][j] = zero;

    const __hip_bfloat16* Arow = hbf + (size_t)lr * 512 + kg;
    const __hip_bfloat16* Brow = Wbf + (size_t)(n0 + wave * 32 + lr) * 512 + kg;
    for (int k0 = 0; k0 < 512; k0 += 32) {
        short8v a[4], b[2];
#pragma unroll
        for (int mf = 0; mf < 4; ++mf)
            a[mf] = *(const short8v*)(Arow + (size_t)mf * 16 * 512 + k0);
#pragma unroll
        for (int nf = 0; nf < 2; ++nf)
            b[nf] = *(const short8v*)(Brow + (size_t)nf * 16 * 512 + k0);
#pragma unroll
        for (int mf = 0; mf < 4; ++mf)
#pragma unroll
            for (int nf = 0; nf < 2; ++nf)
                acc[mf][nf] = __builtin_amdgcn_mfma_f32_16x16x32_bf16(
                    a[mf], b[nf], acc[mf][nf], 0, 0, 0);
    }

    // epilogue: bias + scatter to LDS. D layout: col=lane&15, row=(lane>>4)*4+reg
#pragma unroll
    for (int nf = 0; nf < 2; ++nf) {
        int colLocal = wave * 32 + nf * 16 + lr;
        float bias = genb[n0 + colLocal];
#pragma unroll
        for (int mf = 0; mf < 4; ++mf) {
#pragma unroll
            for (int r = 0; r < 4; ++r) {
                int row = mf * 16 + (lane >> 4) * 4 + r;
                lds[row][colLocal] = acc[mf][nf][r] + bias;
            }
        }
    }
    __syncthreads();

    // per-row (=batch) tile reduction: top-2 + local-max softmax partial + gold
    int row = tid >> 2, q = tid & 3;
    int cbase = q * 32;
    float v1 = -3.4e38f, v2 = -3.4e38f; int i1 = 0x7fffffff, i2 = 0x7fffffff;
    for (int c = 0; c < 32; ++c) {
        float v = lds[row][cbase + c];
        int ci = cbase + c;
        if (v > v1 || (v == v1 && ci < i1)) { v2 = v1; i2 = i1; v1 = v; i1 = ci; }
        else if (v > v2 || (v == v2 && ci < i2)) { v2 = v; i2 = ci; }
    }
    pv1[row][q] = v1; pi1[row][q] = i1; pv2[row][q] = v2; pi2[row][q] = i2;
    __syncthreads();

    float t1 = -3.4e38f, t2 = -3.4e38f; int j1 = 0x7fffffff, j2 = 0x7fffffff;
    if (q == 0) {
        for (int k = 0; k < 4; ++k) {
            float a1 = pv1[row][k]; int a1i = pi1[row][k];
            float a2 = pv2[row][k]; int a2i = pi2[row][k];
            if (a1 > t1 || (a1 == t1 && a1i < j1)) { t2 = t1; j2 = j1; t1 = a1; j1 = a1i; }
            else if (a1 > t2 || (a1 == t2 && a1i < j2)) { t2 = a1; j2 = a1i; }
            if (a2 > t1 || (a2 == t1 && a2i < j1)) { t2 = t1; j2 = j1; t1 = a2; j1 = a2i; }
            else if (a2 > t2 || (a2 == t2 && a2i < j2)) { t2 = a2; j2 = a2i; }
        }
        mrow[row] = t1;
    }
    __syncthreads();
    float m = mrow[row];
    float s = 0.f;
    for (int c = 0; c < 32; ++c) s += expf(lds[row][cbase + c] - m);
    psum[row][q] = s;
    __syncthreads();
    if (q == 0) {
        float sum = psum[row][0] + psum[row][1] + psum[row][2] + psum[row][3];
        int y = y_seqs[row * T + t + 1];
        float gold = (y >= n0 && y < n0 + NT) ? lds[row][y - n0] : 0.f;
        Partial p;
        p.top1 = t1; p.top2 = t2; p.i1 = n0 + j1; p.i2 = n0 + j2;
        p.sumexp = sum; p.gold = gold;
        part[(size_t)blockIdx.x * B + row] = p;
    }
}

// ---------- decoder reduce: combine partials, refine argmax in f32 -------------
__global__ __launch_bounds__(256)
void dec_reduce2_k(const Partial* __restrict__ part,
                   const float* __restrict__ h,      // f32 layer-1 h [64][512]
                   const float* __restrict__ genW,   // f32 [V][512]
                   const float* __restrict__ genb,
                   const int* __restrict__ y_seqs, const int* __restrict__ teacher,
                   int* __restrict__ inp, float* __restrict__ outp, int t)
{
    __shared__ float sM[256], sS[256], sG[256], red[256];
    __shared__ float cV[16], rV[16];
    __shared__ int   cI[16];
    __shared__ int   cN;
    int b = blockIdx.x, tid = threadIdx.x;

    float M = -3.4e38f;
    for (int i = tid; i < NTILES; i += 256) M = fmaxf(M, part[(size_t)i * B + b].top1);
    sM[tid] = M; __syncthreads();
    for (int o = 128; o; o >>= 1) { if (tid < o) sM[tid] = fmaxf(sM[tid], sM[tid + o]); __syncthreads(); }
    M = sM[0];
    if (tid == 0) cN = 0;
    __syncthreads();

    float Ssum = 0.f, G = 0.f;
    for (int i = tid; i < NTILES; i += 256) {
        Partial p = part[(size_t)i * B + b];
        Ssum += p.sumexp * expf(p.top1 - M);
        G += p.gold;
        if (p.top1 >= M - MARGIN) { int j = atomicAdd(&cN, 1); if (j < 16) { cV[j] = p.top1; cI[j] = p.i1; } }
        if (p.top2 >= M - MARGIN) { int j = atomicAdd(&cN, 1); if (j < 16) { cV[j] = p.top2; cI[j] = p.i2; } }
    }
    sS[tid] = Ssum; sG[tid] = G; __syncthreads();
    for (int o = 128; o; o >>= 1) {
        if (tid < o) { sS[tid] += sS[tid + o]; sG[tid] += sG[tid + o]; }
        __syncthreads();
    }
    float lse = M + logf(sS[0]);
    float gold = sG[0];
    int nc = cN < 16 ? cN : 16;

    // f32 refinement of candidates (exact-vs-reference argmax identity)
    if (nc > 1) {
        const float* hrow = h + (size_t)b * 512;
        for (int j = 0; j < nc; ++j) {
            const float* wrow = genW + (size_t)cI[j] * 512;
            float s = 0.f;
            for (int k = tid; k < 512; k += 256) s = fmaf(hrow[k], wrow[k], s);
            red[tid] = s; __syncthreads();
            for (int o = 128; o; o >>= 1) { if (tid < o) red[tid] += red[tid + o]; __syncthreads(); }
            if (tid == 0) rV[j] = red[0] + genb[cI[j]];
            __syncthreads();
        }
    }
    if (tid == 0) {
        int winner;
        if (nc == 1) winner = cI[0];
        else {
            float bv = -3.4e38f; int bi = 0x7fffffff;
            for (int j = 0; j < nc; ++j)
                if (rV[j] > bv || (rV[j] == bv && cI[j] < bi)) { bv = rV[j]; bi = cI[j]; }
            winner = bi;
        }
        int y = y_seqs[b * T + t + 1];
        outp[b * TM1 + t] = gold - lse;
        inp[b] = (teacher[t] > 0) ? y : winner;
    }
}

__global__ void init_inp_k(int* inp) { if (threadIdx.x < B) inp[threadIdx.x] = 1; }

} // namespace

extern "C" void kernel_launch(void* const* d_in, const int* in_sizes, int n_in,
                              void* d_out, int out_size, void* d_ws, size_t ws_size,
                              hipStream_t stream)
{
    (void)in_sizes; (void)n_in; (void)out_size;
    const int*   x_seqs  = (const int*)  d_in[0];
    const int*   x_len   = (const int*)  d_in[1];
    const int*   y_seqs  = (const int*)  d_in[2];
    const int*   teacher = (const int*)  d_in[3];
    const float* src_emb = (const float*)d_in[4];
    const float* tgt_emb = (const float*)d_in[5];
    const float* eWih    = (const float*)d_in[6];
    const float* eWhh    = (const float*)d_in[7];
    const float* eb      = (const float*)d_in[8];
    const float* dWih    = (const float*)d_in[9];
    const float* dWhh    = (const float*)d_in[10];
    const float* db      = (const float*)d_in[11];
    const float* genW    = (const float*)d_in[12];
    const float* genb    = (const float*)d_in[13];
    float* out = (float*)d_out;

    float* w = (float*)d_ws;
    size_t off = 0;
    auto take = [&](size_t n) { float* p = w + off; off += n; return p; };
    float* Xc     = take((size_t)CHUNK * B * G4);   // x-part gates, one chunk (enc only)
    float* out0   = take((size_t)S * B * H);        // encoder layer-0 outputs (enc only)
    float* eWhhT  = take((size_t)2 * E * G4);
    float* dWhhT  = take((size_t)2 * E * G4);
    float* dWihT  = take((size_t)2 * E * G4);
    float* hping  = take(2 * (size_t)BH);
    float* cenc   = take(2 * (size_t)BH);
    float* dech   = take(4 * (size_t)BH);           // [layer][slot][B*H]
    float* decc   = take(2 * (size_t)BH);
    float* hbf_f  = take((size_t)BH / 2);           // bf16 h, 64KB
    float* part_f = take((size_t)NTILES * B * 6);   // Partial[250][64]
    int*   inp    = (int*)take(256);
    if (ws_size < off * sizeof(float)) return;      // fail visibly if ws too small

    // genW bf16 copy OVERLAYS Xc+out0 (33.55MB >= 32.77MB), written after encoder
    __hip_bfloat16* Wbf = (__hip_bfloat16*)Xc;
    __hip_bfloat16* hbf = (__hip_bfloat16*)hbf_f;
    Partial* part = (Partial*)part_f;

    dim3 tpb256(256), tpb32x8(32, 8);
    transpose_k<<<dim3(G4 / 32, E / 32, 2), tpb32x8, 0, stream>>>(eWhh, eWhhT);
    transpose_k<<<dim3(G4 / 32, E / 32, 2), tpb32x8, 0, stream>>>(dWhh, dWhhT);
    transpose_k<<<dim3(G4 / 32, E / 32, 2), tpb32x8, 0, stream>>>(dWih, dWihT);
    hipMemsetAsync(hping, 0, 2 * BH * sizeof(float), stream);
    hipMemsetAsync(cenc,  0, 2 * BH * sizeof(float), stream);

    // ---------------- encoder ---------------------------------------------------
    for (int l = 0; l < 2; ++l) {
        const float* WihL  = eWih  + (size_t)l * G4 * E;
        const float* WhhTL = eWhhT + (size_t)l * E * G4;
        const float* bL    = eb + l * G4;
        float* cL = cenc + (size_t)l * BH;
        float* o0 = (l == 0) ? out0 : nullptr;
        for (int c0 = 0; c0 < S; c0 += CHUNK) {
            if (l == 0)
                gemm_k<<<dim3(G4 / 128, CHUNK * B / 64), tpb256, 0, stream>>>(
                    src_emb, WihL, bL, Xc, G4, 1, x_seqs, c0 * B);
            else
                gemm_k<<<dim3(G4 / 128, CHUNK * B / 64), tpb256, 0, stream>>>(
                    out0 + (size_t)c0 * B * H, WihL, bL, Xc, G4, 0, nullptr, 0);
            for (int t = c0; t < c0 + CHUNK; ++t)
                enc_step_k<<<dim3(8, 16), tpb256, 0, stream>>>(
                    Xc, WhhTL, hping + (size_t)(t & 1) * BH,
                    hping + (size_t)((t + 1) & 1) * BH, cL, o0, x_len, t, t - c0);
        }
        hipMemcpyAsync(dech + (size_t)(l * 2) * BH, hping, BH * sizeof(float),
                       hipMemcpyDeviceToDevice, stream);
        hipMemcpyAsync(decc + (size_t)l * BH, cL, BH * sizeof(float),
                       hipMemcpyDeviceToDevice, stream);
        if (l == 0) hipMemsetAsync(hping, 0, 2 * BH * sizeof(float), stream);
    }

    // genW -> bf16 (after encoder: overwrites Xc/out0 region)
    convert_bf16_k<<<dim3(V * E / 2048), tpb256, 0, stream>>>(genW, Wbf, V * E);

    // ---------------- decoder ---------------------------------------------------
    init_inp_k<<<1, 64, 0, stream>>>(inp);
    for (int t = 0; t < TM1; ++t) {
        int si_ = t & 1, so_ = (t + 1) & 1;
        dec_step_k<<<dim3(8, 16), tpb256, 0, stream>>>(
            tgt_emb, inp, dWihT, dWhhT, db,
            dech + (size_t)si_ * BH, dech + (size_t)so_ * BH, decc, nullptr);
        dec_step_k<<<dim3(8, 16), tpb256, 0, stream>>>(
            dech + (size_t)so_ * BH, nullptr,
            dWihT + (size_t)E * G4, dWhhT + (size_t)E * G4, db + G4,
            dech + (size_t)(2 + si_) * BH, dech + (size_t)(2 + so_) * BH, decc + BH, hbf);
        gen_fused_k<<<dim3(NTILES), tpb256, 0, stream>>>(hbf, Wbf, genb, y_seqs, t, part);
        dec_reduce2_k<<<dim3(B), tpb256, 0, stream>>>(
            part, dech + (size_t)(2 + so_) * BH, genW, genb, y_seqs, teacher, inp, out, t);
    }
}

// Round 3
// 10455.340 us; speedup vs baseline: 1.9070x; 1.5069x over previous
//
#include <hip/hip_runtime.h>
#include <hip/hip_bf16.h>
#include <cstdint>
#include <cstddef>

namespace {

constexpr int B = 64, S = 128, T = 64, V = 32000, E = 512, H = 512;
constexpr int G4 = 2048;
constexpr int TM1 = T - 1;
constexpr int CHUNK = 32;
constexpr int BH = B * H;           // 32768
constexpr int NT = 128;             // generator N-tile
constexpr int NTILES = V / NT;      // 250
constexpr float MARGIN = 0.02f;

typedef __attribute__((ext_vector_type(8))) short short8v;
typedef __attribute__((ext_vector_type(4))) float f32x4;

struct Partial { float top1, top2; int i1, i2; float sumexp, gold; };

__device__ __forceinline__ float sigf(float x) { return 1.0f / (1.0f + expf(-x)); }

__device__ __forceinline__ void split3(float w, __hip_bfloat16& a, __hip_bfloat16& b,
                                       __hip_bfloat16& c2) {
    a = __float2bfloat16(w);
    float r = w - __bfloat162float(a);
    b = __float2bfloat16(r);
    c2 = __float2bfloat16(r - __bfloat162float(b));
}

// ---------- one-time: split+interleave decoder weights [Whh|Wih] rows ----------
// out rows j' = kh*4+g (gates interleaved), K=1024: k<512 Whh, k>=512 Wih
__global__ __launch_bounds__(256)
void split_dec_k(const float* __restrict__ Wih, const float* __restrict__ Whh,
                 const float* __restrict__ bsrc,
                 __hip_bfloat16* __restrict__ P0, __hip_bfloat16* __restrict__ P1,
                 __hip_bfloat16* __restrict__ P2, float* __restrict__ bint)
{
    int row = blockIdx.x;                 // l*2048 + j'
    int l = row >> 11, jp = row & 2047;
    int kh = jp >> 2, g = jp & 3, src = g * 512 + kh;
    const float* wih = Wih + ((size_t)l * 2048 + src) * 512;
    const float* whh = Whh + ((size_t)l * 2048 + src) * 512;
    size_t ro = (size_t)row * 1024;
    for (int k = threadIdx.x; k < 1024; k += 256) {
        float w = (k < 512) ? whh[k] : wih[k - 512];
        __hip_bfloat16 a, b, c2; split3(w, a, b, c2);
        P0[ro + k] = a; P1[ro + k] = b; P2[ro + k] = c2;
    }
    if (threadIdx.x == 0) bint[row] = bsrc[l * 2048 + src];
}

// ---------- one-time: split+interleave encoder Whh, K=512 ----------
__global__ __launch_bounds__(256)
void split_enc_k(const float* __restrict__ Whh,
                 __hip_bfloat16* __restrict__ P0, __hip_bfloat16* __restrict__ P1,
                 __hip_bfloat16* __restrict__ P2)
{
    int row = blockIdx.x;
    int l = row >> 11, jp = row & 2047;
    int kh = jp >> 2, g = jp & 3, src = g * 512 + kh;
    const float* whh = Whh + ((size_t)l * 2048 + src) * 512;
    size_t ro = (size_t)row * 512;
    for (int k = threadIdx.x; k < 512; k += 256) {
        __hip_bfloat16 a, b, c2; split3(whh[k], a, b, c2);
        P0[ro + k] = a; P1[ro + k] = b; P2[ro + k] = c2;
    }
}

// ---------- f32 GEMM (encoder x-part), optional col-interleave on write -------
__global__ __launch_bounds__(256)
void gemm_k(const float* __restrict__ A, const float* __restrict__ Wt,
            const float* __restrict__ bias, float* __restrict__ C,
            int N, int tokmode, const int* __restrict__ xseq, int m0)
{
    constexpr int K = 512, BM = 64, BN = 128, BK = 16;
    __shared__ __align__(16) float As[BK][BM + 4];
    __shared__ __align__(16) float Bs[BK][BN + 4];
    int tid = threadIdx.x;
    int bm = blockIdx.y * BM, bn = blockIdx.x * BN;
    int tx = tid & 15, ty = tid >> 4;
    float acc[4][8] = {};

    int lm = tid >> 2, lk = (tid & 3) << 2;
    const float* Arow;
    {
        int m = bm + lm;
        if (tokmode) { int mg = m0 + m; int tt = mg >> 6, b = mg & 63;
                       Arow = A + (size_t)xseq[b * S + tt] * K; }
        else Arow = A + (size_t)m * K;
    }
    int ln = tid >> 1, lkb = (tid & 1) << 3;
    const float* Brow = Wt + (size_t)(bn + ln) * K;

    for (int k0 = 0; k0 < K; k0 += BK) {
        float4 av = *(const float4*)(Arow + k0 + lk);
        As[lk + 0][lm] = av.x; As[lk + 1][lm] = av.y;
        As[lk + 2][lm] = av.z; As[lk + 3][lm] = av.w;
        float4 bv0 = *(const float4*)(Brow + k0 + lkb);
        float4 bv1 = *(const float4*)(Brow + k0 + lkb + 4);
        Bs[lkb + 0][ln] = bv0.x; Bs[lkb + 1][ln] = bv0.y;
        Bs[lkb + 2][ln] = bv0.z; Bs[lkb + 3][ln] = bv0.w;
        Bs[lkb + 4][ln] = bv1.x; Bs[lkb + 5][ln] = bv1.y;
        Bs[lkb + 6][ln] = bv1.z; Bs[lkb + 7][ln] = bv1.w;
        __syncthreads();
#pragma unroll
        for (int kk = 0; kk < BK; ++kk) {
            const float4 a4  = *(const float4*)&As[kk][ty * 4];
            const float4 b4a = *(const float4*)&Bs[kk][tx * 8];
            const float4 b4b = *(const float4*)&Bs[kk][tx * 8 + 4];
            const float a[4]  = {a4.x, a4.y, a4.z, a4.w};
            const float bb[8] = {b4a.x, b4a.y, b4a.z, b4a.w,
                                 b4b.x, b4b.y, b4b.z, b4b.w};
#pragma unroll
            for (int i = 0; i < 4; ++i)
#pragma unroll
                for (int j = 0; j < 8; ++j)
                    acc[i][j] = fmaf(a[i], bb[j], acc[i][j]);
        }
        __syncthreads();
    }
#pragma unroll
    for (int i = 0; i < 4; ++i) {
        size_t crow = (size_t)(bm + ty * 4 + i) * N;
#pragma unroll
        for (int j = 0; j < 8; ++j) {
            int cg = bn + tx * 8 + j;
            int jp = ((cg & 511) << 2) | (cg >> 9);   // interleave gates
            C[crow + jp] = acc[i][j] + bias[cg];
        }
    }
}

// ---------- LSTM step via 3-way-split bf16 MFMA (f32-accurate) -----------------
// grid 128 blocks x 256 thr. Block: 16 interleaved gate-cols (4 kh x 4 gates),
// wave = 1 M-tile (16 batches). KHALF=1: K=512 (h only, enc); 2: K=1024 (h|x).
template<int KHALF, bool ENC>
__global__ __launch_bounds__(256)
void step_k(const __hip_bfloat16* __restrict__ hA0, const __hip_bfloat16* __restrict__ hA1,
            const __hip_bfloat16* __restrict__ hA2,
            const __hip_bfloat16* __restrict__ xA0, const __hip_bfloat16* __restrict__ xA1,
            const __hip_bfloat16* __restrict__ xA2,
            const __hip_bfloat16* __restrict__ W0, const __hip_bfloat16* __restrict__ W1,
            const __hip_bfloat16* __restrict__ W2,
            const float* __restrict__ XcOrBias,    // enc: Xc row-base (interleaved, +bias); dec: bint
            const float* __restrict__ h_in, float* __restrict__ h_out,
            float* __restrict__ c,
            __hip_bfloat16* __restrict__ o0, __hip_bfloat16* __restrict__ o1,
            __hip_bfloat16* __restrict__ o2,
            float* __restrict__ out0, const int* __restrict__ x_len, int t, int tloc)
{
    __shared__ float gs[64][17];
    int tid = threadIdx.x;
    int wave = tid >> 6, lane = tid & 63;
    int lr = lane & 15, kg = (lane >> 4) * 8;
    int arow = wave * 16 + lr;                    // batch
    int brow = blockIdx.x * 16 + lr;              // interleaved gate col j'
    const int KW = 512 * KHALF;

    f32x4 acc0 = {0,0,0,0}, acc1 = {0,0,0,0}, acc2 = {0,0,0,0};
    const size_t aoff = (size_t)arow * 512 + kg;
    const size_t boff = (size_t)brow * KW + kg;

#pragma unroll
    for (int kk = 0; kk < KHALF * 16; ++kk) {
        int k0 = kk * 32;
        const __hip_bfloat16 *A0, *A1, *A2; int ka;
        if (KHALF == 2 && kk >= 16) { A0 = xA0; A1 = xA1; A2 = xA2; ka = k0 - 512; }
        else                        { A0 = hA0; A1 = hA1; A2 = hA2; ka = k0; }
        short8v a0 = *(const short8v*)(A0 + aoff + ka);
        short8v a1 = *(const short8v*)(A1 + aoff + ka);
        short8v a2 = *(const short8v*)(A2 + aoff + ka);
        short8v b0 = *(const short8v*)(W0 + boff + k0);
        short8v b1 = *(const short8v*)(W1 + boff + k0);
        short8v b2 = *(const short8v*)(W2 + boff + k0);
        acc0 = __builtin_amdgcn_mfma_f32_16x16x32_bf16(a0, b0, acc0, 0, 0, 0);
        acc1 = __builtin_amdgcn_mfma_f32_16x16x32_bf16(a0, b1, acc1, 0, 0, 0);
        acc2 = __builtin_amdgcn_mfma_f32_16x16x32_bf16(a1, b0, acc2, 0, 0, 0);
        acc0 = __builtin_amdgcn_mfma_f32_16x16x32_bf16(a1, b1, acc0, 0, 0, 0);
        acc1 = __builtin_amdgcn_mfma_f32_16x16x32_bf16(a0, b2, acc1, 0, 0, 0);
        acc2 = __builtin_amdgcn_mfma_f32_16x16x32_bf16(a2, b0, acc2, 0, 0, 0);
    }
    int rb = (lane >> 4) * 4;
#pragma unroll
    for (int r = 0; r < 4; ++r)
        gs[wave * 16 + rb + r][lr] = acc0[r] + acc1[r] + acc2[r];
    __syncthreads();

    int b = tid >> 2, khl = tid & 3;
    int khg = blockIdx.x * 4 + khl;
    float4 add;
    if (ENC) add = *(const float4*)(XcOrBias + (size_t)b * G4 + (size_t)khg * 4);
    else     add = *(const float4*)(XcOrBias + (size_t)khg * 4);
    float gi = gs[b][khl * 4 + 0] + add.x;
    float gf = gs[b][khl * 4 + 1] + add.y;
    float gg = gs[b][khl * 4 + 2] + add.z;
    float go = gs[b][khl * 4 + 3] + add.w;
    size_t idx = (size_t)b * H + khg;
    float cold = c[idx];
    float c2 = sigf(gf) * cold + sigf(gi) * tanhf(gg);
    float h2 = sigf(go) * tanhf(c2);
    if (ENC) {
        bool mk = t < x_len[b];
        if (!mk) { h2 = h_in[idx]; c2 = cold; }
    }
    h_out[idx] = h2;
    c[idx] = c2;
    __hip_bfloat16 s0, s1, s2; split3(h2, s0, s1, s2);
    o0[idx] = s0; o1[idx] = s1; o2[idx] = s2;
    if (ENC && out0) out0[(size_t)(t * B + b) * H + khg] = h2;
}

// ---------- f32 -> bf16 convert (genW) ----------
__global__ __launch_bounds__(256)
void convert_bf16_k(const float* __restrict__ src, __hip_bfloat16* __restrict__ dst, int n)
{
    int i = (blockIdx.x * 256 + threadIdx.x) * 8;
    if (i + 8 > n) return;
    float4 a = *(const float4*)(src + i);
    float4 b = *(const float4*)(src + i + 4);
    __hip_bfloat16 tmp[8];
    tmp[0] = __float2bfloat16(a.x); tmp[1] = __float2bfloat16(a.y);
    tmp[2] = __float2bfloat16(a.z); tmp[3] = __float2bfloat16(a.w);
    tmp[4] = __float2bfloat16(b.x); tmp[5] = __float2bfloat16(b.y);
    tmp[6] = __float2bfloat16(b.z); tmp[7] = __float2bfloat16(b.w);
    *(short8v*)(dst + i) = *(const short8v*)tmp;
}

// ---------- generator: bf16 MFMA GEMM + fused per-tile softmax partials --------
__global__ __launch_bounds__(256)
void gen_fused_k(const __hip_bfloat16* __restrict__ hbf,
                 const __hip_bfloat16* __restrict__ Wbf,
                 const float* __restrict__ genb,
                 const int* __restrict__ y_seqs, int t,
                 Partial* __restrict__ part)
{
    __shared__ float lds[64][NT + 4];
    __shared__ float pv1[64][4], pv2[64][4], psum[64][4], mrow[64];
    __shared__ int   pi1[64][4], pi2[64][4];

    int tid = threadIdx.x;
    int wave = tid >> 6, lane = tid & 63;
    int n0 = blockIdx.x * NT;
    int lr = lane & 15;
    int kg = (lane >> 4) * 8;

    f32x4 acc[4][2];
    const f32x4 zero = {0.f, 0.f, 0.f, 0.f};
#pragma unroll
    for (int i = 0; i < 4; ++i)
#pragma unroll
        for (int j = 0; j < 2; ++j) acc[i][j] = zero;

    const __hip_bfloat16* Arow = hbf + (size_t)lr * 512 + kg;
    const __hip_bfloat16* Brow = Wbf + (size_t)(n0 + wave * 32 + lr) * 512 + kg;
    for (int k0 = 0; k0 < 512; k0 += 32) {
        short8v a[4], b[2];
#pragma unroll
        for (int mf = 0; mf < 4; ++mf)
            a[mf] = *(const short8v*)(Arow + (size_t)mf * 16 * 512 + k0);
#pragma unroll
        for (int nf = 0; nf < 2; ++nf)
            b[nf] = *(const short8v*)(Brow + (size_t)nf * 16 * 512 + k0);
#pragma unroll
        for (int mf = 0; mf < 4; ++mf)
#pragma unroll
            for (int nf = 0; nf < 2; ++nf)
                acc[mf][nf] = __builtin_amdgcn_mfma_f32_16x16x32_bf16(
                    a[mf], b[nf], acc[mf][nf], 0, 0, 0);
    }
#pragma unroll
    for (int nf = 0; nf < 2; ++nf) {
        int colLocal = wave * 32 + nf * 16 + lr;
        float bias = genb[n0 + colLocal];
#pragma unroll
        for (int mf = 0; mf < 4; ++mf) {
#pragma unroll
            for (int r = 0; r < 4; ++r) {
                int row = mf * 16 + (lane >> 4) * 4 + r;
                lds[row][colLocal] = acc[mf][nf][r] + bias;
            }
        }
    }
    __syncthreads();

    int row = tid >> 2, q = tid & 3;
    int cbase = q * 32;
    float v1 = -3.4e38f, v2 = -3.4e38f; int i1 = 0x7fffffff, i2 = 0x7fffffff;
    for (int c = 0; c < 32; ++c) {
        float v = lds[row][cbase + c];
        int ci = cbase + c;
        if (v > v1 || (v == v1 && ci < i1)) { v2 = v1; i2 = i1; v1 = v; i1 = ci; }
        else if (v > v2 || (v == v2 && ci < i2)) { v2 = v; i2 = ci; }
    }
    pv1[row][q] = v1; pi1[row][q] = i1; pv2[row][q] = v2; pi2[row][q] = i2;
    __syncthreads();

    float t1 = -3.4e38f, t2 = -3.4e38f; int j1 = 0x7fffffff, j2 = 0x7fffffff;
    if (q == 0) {
        for (int k = 0; k < 4; ++k) {
            float a1 = pv1[row][k]; int a1i = pi1[row][k];
            float a2 = pv2[row][k]; int a2i = pi2[row][k];
            if (a1 > t1 || (a1 == t1 && a1i < j1)) { t2 = t1; j2 = j1; t1 = a1; j1 = a1i; }
            else if (a1 > t2 || (a1 == t2 && a1i < j2)) { t2 = a1; j2 = a1i; }
            if (a2 > t1 || (a2 == t1 && a2i < j1)) { t2 = t1; j2 = j1; t1 = a2; j1 = a2i; }
            else if (a2 > t2 || (a2 == t2 && a2i < j2)) { t2 = a2; j2 = a2i; }
        }
        mrow[row] = t1;
    }
    __syncthreads();
    float m = mrow[row];
    float s = 0.f;
    for (int c = 0; c < 32; ++c) s += expf(lds[row][cbase + c] - m);
    psum[row][q] = s;
    __syncthreads();
    if (q == 0) {
        float sum = psum[row][0] + psum[row][1] + psum[row][2] + psum[row][3];
        Partial p;
        p.top1 = t1; p.top2 = t2; p.i1 = n0 + j1; p.i2 = n0 + j2;
        p.sumexp = sum; p.gold = 0.f;
        part[(size_t)blockIdx.x * B + row] = p;
    }
}

// ---------- reduce: combine partials, exact-f32 argmax + gold, emit x-splits ---
__global__ __launch_bounds__(256)
void dec_reduce2_k(const Partial* __restrict__ part,
                   const float* __restrict__ h,       // f32 dec L1 h [64][512]
                   const float* __restrict__ genW, const float* __restrict__ genb,
                   const float* __restrict__ tgt_emb,
                   const int* __restrict__ y_seqs, const int* __restrict__ teacher,
                   float* __restrict__ outp,
                   __hip_bfloat16* __restrict__ xp0, __hip_bfloat16* __restrict__ xp1,
                   __hip_bfloat16* __restrict__ xp2, int t)
{
    __shared__ float sM[256], sS[256], red[256];
    __shared__ float cV[16], rV[16];
    __shared__ int   cI[16];
    __shared__ int   cN, nxt;
    int b = blockIdx.x, tid = threadIdx.x;
    int y = y_seqs[b * T + t + 1];
    const float* hrow = h + (size_t)b * 512;

    float M = -3.4e38f;
    for (int i = tid; i < NTILES; i += 256) M = fmaxf(M, part[(size_t)i * B + b].top1);
    sM[tid] = M; __syncthreads();
    for (int o = 128; o; o >>= 1) { if (tid < o) sM[tid] = fmaxf(sM[tid], sM[tid + o]); __syncthreads(); }
    M = sM[0];
    if (tid == 0) cN = 0;
    __syncthreads();

    float Ssum = 0.f;
    for (int i = tid; i < NTILES; i += 256) {
        Partial p = part[(size_t)i * B + b];
        Ssum += p.sumexp * expf(p.top1 - M);
        if (p.top1 >= M - MARGIN) { int j = atomicAdd(&cN, 1); if (j < 16) { cV[j] = p.top1; cI[j] = p.i1; } }
        if (p.top2 >= M - MARGIN) { int j = atomicAdd(&cN, 1); if (j < 16) { cV[j] = p.top2; cI[j] = p.i2; } }
    }
    sS[tid] = Ssum; __syncthreads();
    for (int o = 128; o; o >>= 1) { if (tid < o) sS[tid] += sS[tid + o]; __syncthreads(); }
    float lse = M + logf(sS[0]);
    int nc = cN < 16 ? cN : 16;

    // exact f32 gold logit
    {
        const float* wrow = genW + (size_t)y * 512;
        float s = 0.f;
        for (int k = tid; k < 512; k += 256) s = fmaf(hrow[k], wrow[k], s);
        red[tid] = s; __syncthreads();
        for (int o = 128; o; o >>= 1) { if (tid < o) red[tid] += red[tid + o]; __syncthreads(); }
        if (tid == 0) outp[b * TM1 + t] = red[0] + genb[y] - lse;
        __syncthreads();
    }
    // exact f32 refinement of argmax candidates
    if (nc > 1) {
        for (int j = 0; j < nc; ++j) {
            const float* wrow = genW + (size_t)cI[j] * 512;
            float s = 0.f;
            for (int k = tid; k < 512; k += 256) s = fmaf(hrow[k], wrow[k], s);
            red[tid] = s; __syncthreads();
            for (int o = 128; o; o >>= 1) { if (tid < o) red[tid] += red[tid + o]; __syncthreads(); }
            if (tid == 0) rV[j] = red[0] + genb[cI[j]];
            __syncthreads();
        }
    }
    if (tid == 0) {
        int winner;
        if (nc == 1) winner = cI[0];
        else {
            float bv = -3.4e38f; int bi = 0x7fffffff;
            for (int j = 0; j < nc; ++j)
                if (rV[j] > bv || (rV[j] == bv && cI[j] < bi)) { bv = rV[j]; bi = cI[j]; }
            winner = bi;
        }
        nxt = (teacher[t] > 0) ? y : winner;
    }
    __syncthreads();
    int tok = nxt;
    for (int k = tid; k < 512; k += 256) {
        float w = tgt_emb[(size_t)tok * 512 + k];
        __hip_bfloat16 s0, s1, s2; split3(w, s0, s1, s2);
        xp0[(size_t)b * 512 + k] = s0;
        xp1[(size_t)b * 512 + k] = s1;
        xp2[(size_t)b * 512 + k] = s2;
    }
}

// ---------- init: x-splits for t=0 (BOS token = 1) ----------
__global__ __launch_bounds__(256)
void init_x_k(const float* __restrict__ tgt_emb,
              __hip_bfloat16* __restrict__ xp0, __hip_bfloat16* __restrict__ xp1,
              __hip_bfloat16* __restrict__ xp2)
{
    int b = blockIdx.x;
    for (int k = threadIdx.x; k < 512; k += 256) {
        float w = tgt_emb[512 + k];                // token 1 (BOS)
        __hip_bfloat16 s0, s1, s2; split3(w, s0, s1, s2);
        xp0[(size_t)b * 512 + k] = s0;
        xp1[(size_t)b * 512 + k] = s1;
        xp2[(size_t)b * 512 + k] = s2;
    }
}

} // namespace

extern "C" void kernel_launch(void* const* d_in, const int* in_sizes, int n_in,
                              void* d_out, int out_size, void* d_ws, size_t ws_size,
                              hipStream_t stream)
{
    (void)in_sizes; (void)n_in; (void)out_size;
    const int*   x_seqs  = (const int*)  d_in[0];
    const int*   x_len   = (const int*)  d_in[1];
    const int*   y_seqs  = (const int*)  d_in[2];
    const int*   teacher = (const int*)  d_in[3];
    const float* src_emb = (const float*)d_in[4];
    const float* tgt_emb = (const float*)d_in[5];
    const float* eWih    = (const float*)d_in[6];
    const float* eWhh    = (const float*)d_in[7];
    const float* eb      = (const float*)d_in[8];
    const float* dWih    = (const float*)d_in[9];
    const float* dWhh    = (const float*)d_in[10];
    const float* db      = (const float*)d_in[11];
    const float* genW    = (const float*)d_in[12];
    const float* genb    = (const float*)d_in[13];
    float* out = (float*)d_out;

    float* w = (float*)d_ws;
    size_t off = 0;
    auto take = [&](size_t n) { float* p = w + off; off += n; return p; };
    // bf16 plane helper: n bf16 elements -> ceil(n/2) floats
    auto takeb = [&](size_t n) { return (__hip_bfloat16*)take((n + 1) / 2); };

    float* Xc     = take((size_t)CHUNK * B * G4);   // 16.8MB (enc) -- overlaid by Wbf
    float* out0   = take((size_t)S * B * H);        // 16.8MB (enc) -- overlaid by Wbf
    __hip_bfloat16* eP0 = takeb((size_t)2 * G4 * 512);
    __hip_bfloat16* eP1 = takeb((size_t)2 * G4 * 512);
    __hip_bfloat16* eP2 = takeb((size_t)2 * G4 * 512);
    __hip_bfloat16* dP0 = takeb((size_t)2 * G4 * 1024);
    __hip_bfloat16* dP1 = takeb((size_t)2 * G4 * 1024);
    __hip_bfloat16* dP2 = takeb((size_t)2 * G4 * 1024);
    float* bint   = take(2 * (size_t)G4);
    float* hping  = take(2 * (size_t)BH);           // enc f32 h ping-pong
    float* cenc   = take(2 * (size_t)BH);
    float* decc   = take(2 * (size_t)BH);
    float* dech0  = take((size_t)BH);               // dec L0 f32 h
    float* dech1  = take((size_t)BH);               // dec L1 f32 h
    __hip_bfloat16* encP   = takeb((size_t)2 * 3 * BH);   // [slot][plane][BH]
    __hip_bfloat16* decL0P = takeb((size_t)2 * 3 * BH);
    __hip_bfloat16* decL1P = takeb((size_t)2 * 3 * BH);
    __hip_bfloat16* xP     = takeb((size_t)3 * BH);
    float* part_f = take((size_t)NTILES * B * 6);
    if (ws_size < off * sizeof(float)) return;      // fail visibly if ws too small

    __hip_bfloat16* Wbf = (__hip_bfloat16*)Xc;      // genW bf16 overlays Xc+out0
    Partial* part = (Partial*)part_f;
    auto encPl = [&](int slot, int pl) { return encP   + ((size_t)slot * 3 + pl) * BH; };
    auto d0Pl  = [&](int slot, int pl) { return decL0P + ((size_t)slot * 3 + pl) * BH; };
    auto d1Pl  = [&](int slot, int pl) { return decL1P + ((size_t)slot * 3 + pl) * BH; };

    dim3 tpb256(256);

    // one-time weight splits
    split_enc_k<<<dim3(2 * G4), tpb256, 0, stream>>>(eWhh, eP0, eP1, eP2);
    split_dec_k<<<dim3(2 * G4), tpb256, 0, stream>>>(dWih, dWhh, db, dP0, dP1, dP2, bint);
    hipMemsetAsync(hping, 0, 2 * BH * sizeof(float), stream);
    hipMemsetAsync(cenc,  0, 2 * BH * sizeof(float), stream);

    // ---------------- encoder ----------------
    for (int l = 0; l < 2; ++l) {
        const float* WihL = eWih + (size_t)l * G4 * E;
        const float* bL   = eb + l * G4;
        const __hip_bfloat16* W0 = eP0 + (size_t)l * G4 * 512;
        const __hip_bfloat16* W1 = eP1 + (size_t)l * G4 * 512;
        const __hip_bfloat16* W2 = eP2 + (size_t)l * G4 * 512;
        float* cL = cenc + (size_t)l * BH;
        float* o0 = (l == 0) ? out0 : nullptr;
        hipMemsetAsync(encP, 0, 3 * BH * sizeof(__hip_bfloat16), stream);  // slot0 = zeros
        for (int c0 = 0; c0 < S; c0 += CHUNK) {
            if (l == 0)
                gemm_k<<<dim3(G4 / 128, CHUNK * B / 64), tpb256, 0, stream>>>(
                    src_emb, WihL, bL, Xc, G4, 1, x_seqs, c0 * B);
            else
                gemm_k<<<dim3(G4 / 128, CHUNK * B / 64), tpb256, 0, stream>>>(
                    out0 + (size_t)c0 * B * H, WihL, bL, Xc, G4, 0, nullptr, 0);
            for (int t = c0; t < c0 + CHUNK; ++t) {
                int si = t & 1, so = (t + 1) & 1;
                step_k<1, true><<<dim3(128), tpb256, 0, stream>>>(
                    encPl(si, 0), encPl(si, 1), encPl(si, 2),
                    nullptr, nullptr, nullptr, W0, W1, W2,
                    Xc + (size_t)(t - c0) * B * G4,
                    hping + (size_t)si * BH, hping + (size_t)so * BH, cL,
                    encPl(so, 0), encPl(so, 1), encPl(so, 2),
                    o0, x_len, t, t - c0);
            }
        }
        // final state: f32 h slot0 / planes slot0 ((S-1)+1 & 1 == 0)
        hipMemcpyAsync((l == 0 ? decL0P : decL1P), encP,
                       3 * BH * sizeof(__hip_bfloat16), hipMemcpyDeviceToDevice, stream);
        hipMemcpyAsync(decc + (size_t)l * BH, cL, BH * sizeof(float),
                       hipMemcpyDeviceToDevice, stream);
        if (l == 0) hipMemsetAsync(hping, 0, 2 * BH * sizeof(float), stream);
    }

    // genW -> bf16 (overlays Xc/out0, both dead now)
    convert_bf16_k<<<dim3(V * E / 2048), tpb256, 0, stream>>>(genW, Wbf, V * E);
    init_x_k<<<dim3(B), tpb256, 0, stream>>>(tgt_emb, xP, xP + BH, xP + 2 * BH);

    // ---------------- decoder ----------------
    for (int t = 0; t < TM1; ++t) {
        int si = t & 1, so = (t + 1) & 1;
        step_k<2, false><<<dim3(128), tpb256, 0, stream>>>(
            d0Pl(si, 0), d0Pl(si, 1), d0Pl(si, 2),
            xP, xP + BH, xP + 2 * BH,
            dP0, dP1, dP2, bint,
            nullptr, dech0, decc,
            d0Pl(so, 0), d0Pl(so, 1), d0Pl(so, 2),
            nullptr, nullptr, 0, 0);
        step_k<2, false><<<dim3(128), tpb256, 0, stream>>>(
            d1Pl(si, 0), d1Pl(si, 1), d1Pl(si, 2),
            d0Pl(so, 0), d0Pl(so, 1), d0Pl(so, 2),
            dP0 + (size_t)G4 * 1024, dP1 + (size_t)G4 * 1024, dP2 + (size_t)G4 * 1024,
            bint + G4,
            nullptr, dech1, decc + BH,
            d1Pl(so, 0), d1Pl(so, 1), d1Pl(so, 2),
            nullptr, nullptr, 0, 0);
        gen_fused_k<<<dim3(NTILES), tpb256, 0, stream>>>(
            d1Pl(so, 0), Wbf, genb, y_seqs, t, part);
        dec_reduce2_k<<<dim3(B), tpb256, 0, stream>>>(
            part, dech1, genW, genb, tgt_emb, y_seqs, teacher, out,
            xP, xP + BH, xP + 2 * BH, t);
    }
}